// Round 7
// baseline (880.784 us; speedup 1.0000x reference)
//
#include <hip/hip_runtime.h>
#include <math.h>

#define NT 65536
#define EE 1048576
#define NB 128
#define KK 410          // kept nodes per graph = ceil(0.8*512)
#define HH 128

typedef short bf16x8 __attribute__((ext_vector_type(8)));
typedef float f32x4 __attribute__((ext_vector_type(4)));

// ---------------- device scratch -------------------------------------------
__device__ unsigned short g_xb[(size_t)NT * 64];
__device__ unsigned short g_hb1[(size_t)NT * HH];
__device__ unsigned short g_hb2[(size_t)NT * HH];
__device__ unsigned short g_wt1[128 * 128];
__device__ unsigned short g_wtc[3 * 128 * 256];
__device__ unsigned short g_csr1u[EE];   // src id per edge, grouped by dst
__device__ unsigned short g_keptu[NT];   // 1 if node kept by SAGPool
__device__ unsigned int g_ebuck[EE];     // packed (dstLocal<<16)|src, bucketed by graph
__device__ int g_bcnt[128];              // zero at load; reset by scan block each launch
__device__ int g_bbase[129];
__device__ int g_bcur[128];
__device__ int g_done = 0;               // last-block counter; self-restoring
__device__ float g_trel[NT];
__device__ float g_troot[NT];
__device__ float g_gatef[NT];            // tanh(score) if kept else 0
__device__ float g_kinv[NT];             // 1/max(kept-neighbor count,1)
__device__ float g_xc4[4 * NB * 4 * 128]; // pooled partials [sec][graph][quarter][128]
__device__ int g_rows1[NT + 1];

__device__ __forceinline__ unsigned short* ubuf(int id) {
    switch (id) {
        case 0: return g_xb;
        case 1: return g_hb1;
        case 2: return g_hb2;
        case 3: return g_wt1;
        case 4: return g_wtc;
    }
    return g_xb;
}

__device__ __forceinline__ float b2f(unsigned short u) {
    union { unsigned int i; float f; } v;
    v.i = ((unsigned int)u) << 16;
    return v.f;
}
__device__ __forceinline__ unsigned short f2b(float f) {
    unsigned int x = __float_as_uint(f);
    unsigned int r = x + 0x7fffu + ((x >> 16) & 1u);   // round-to-nearest-even
    return (unsigned short)(r >> 16);
}
__device__ __forceinline__ bf16x8 scale8(bf16x8 a, float g) {
    bf16x8 r;
#pragma unroll
    for (int i = 0; i < 8; i++) {
        unsigned short u = (unsigned short)a[i];
        r[i] = (short)f2b(b2f(u) * g);
    }
    return r;
}

// ---------------- prep + bhist + (last block) bucket scan -------------------
// blocks [0,4544): prep (x->bf16, weights->bf16 [n][K])
// blocks [4544,5568): per-graph bucket histogram of dst
// last finishing block: 128-scan of g_bcnt -> g_bbase/g_bcur, reset bcnt/done
__global__ __launch_bounds__(256) void k_preph(const float* __restrict__ x,
                                               const float* __restrict__ W1r,
                                               const float* __restrict__ W1o,
                                               const float* __restrict__ Wcr,
                                               const float* __restrict__ Wco,
                                               const int* __restrict__ dst) {
    __shared__ int h[128];
    __shared__ int lastS;
    __shared__ int s[128];
    if (blockIdx.x < 4544) {
        int tid = blockIdx.x * 256 + threadIdx.x;
        if (tid < 1048576) {
            float4 v = *(const float4*)&x[(size_t)tid * 4];
            unsigned int lo = (unsigned int)f2b(v.x) | ((unsigned int)f2b(v.y) << 16);
            unsigned int hi = (unsigned int)f2b(v.z) | ((unsigned int)f2b(v.w) << 16);
            *(uint2*)&g_xb[(size_t)tid * 4] = make_uint2(lo, hi);
        } else if (tid < 1048576 + 16384) {
            int r = tid - 1048576;
            int k = r & 127, n = r >> 7;
            float v = (k < 64) ? W1r[k * 128 + n] : W1o[(k - 64) * 128 + n];
            g_wt1[n * 128 + k] = f2b(v);
        } else {
            int r = tid - (1048576 + 16384);
            int l = r >> 15;
            int k = r & 255, n = (r >> 8) & 127;
            float v = (k < 128) ? Wcr[l * 16384 + k * 128 + n]
                                : Wco[l * 16384 + (k - 128) * 128 + n];
            g_wtc[l * 32768 + n * 256 + k] = f2b(v);
        }
    } else {
        if (threadIdx.x < 128) h[threadIdx.x] = 0;
        __syncthreads();
        int e0 = ((blockIdx.x - 4544) * 256 + threadIdx.x) * 4;
        int4 d = *(const int4*)&dst[e0];
        atomicAdd(&h[d.x >> 9], 1);
        atomicAdd(&h[d.y >> 9], 1);
        atomicAdd(&h[d.z >> 9], 1);
        atomicAdd(&h[d.w >> 9], 1);
        __syncthreads();
        if (threadIdx.x < 128 && h[threadIdx.x]) atomicAdd(&g_bcnt[threadIdx.x], h[threadIdx.x]);
    }
    // ---- last-block bucket scan ----
    __threadfence();
    if (threadIdx.x == 0) {
        int old = atomicAdd(&g_done, 1);
        lastS = (old == (int)gridDim.x - 1) ? 1 : 0;
    }
    __syncthreads();
    if (lastS) {
        int t = threadIdx.x;
        int v = 0;
        if (t < 128) { v = atomicAdd(&g_bcnt[t], 0); s[t] = v; }
        __syncthreads();
        for (int off = 1; off < 128; off <<= 1) {
            int u = (t >= off && t < 128) ? s[t - off] : 0;
            __syncthreads();
            if (t < 128) s[t] += u;
            __syncthreads();
        }
        if (t < 128) {
            g_bbase[t] = s[t] - v;
            g_bcur[t] = s[t] - v;
            if (t == 127) g_bbase[128] = s[127];
            g_bcnt[t] = 0;                 // consumed next launch (kernel-boundary visible)
        }
        if (t == 0) g_done = 0;
    }
}

// ---------------- CSR1 build phase B/C --------------------------------------
__global__ __launch_bounds__(256) void k_bscatter(const int* __restrict__ src,
                                                  const int* __restrict__ dst) {
    __shared__ int h[128];
    __shared__ int base[128];
    if (threadIdx.x < 128) h[threadIdx.x] = 0;
    __syncthreads();
    int e0 = (blockIdx.x * 256 + threadIdx.x) * 4;
    int4 s = *(const int4*)&src[e0];
    int4 d = *(const int4*)&dst[e0];
    int b0 = d.x >> 9, b1 = d.y >> 9, b2 = d.z >> 9, b3 = d.w >> 9;
    atomicAdd(&h[b0], 1);
    atomicAdd(&h[b1], 1);
    atomicAdd(&h[b2], 1);
    atomicAdd(&h[b3], 1);
    __syncthreads();
    if (threadIdx.x < 128) {
        int c = h[threadIdx.x];
        base[threadIdx.x] = c ? atomicAdd(&g_bcur[threadIdx.x], c) : 0;
        h[threadIdx.x] = 0;
    }
    __syncthreads();
    int r0 = atomicAdd(&h[b0], 1);
    g_ebuck[base[b0] + r0] = ((unsigned int)(d.x & 511) << 16) | (unsigned int)s.x;
    int r1 = atomicAdd(&h[b1], 1);
    g_ebuck[base[b1] + r1] = ((unsigned int)(d.y & 511) << 16) | (unsigned int)s.y;
    int r2 = atomicAdd(&h[b2], 1);
    g_ebuck[base[b2] + r2] = ((unsigned int)(d.z & 511) << 16) | (unsigned int)s.z;
    int r3 = atomicAdd(&h[b3], 1);
    g_ebuck[base[b3] + r3] = ((unsigned int)(d.w & 511) << 16) | (unsigned int)s.w;
}

__global__ __launch_bounds__(512) void k_bcsr() {
    __shared__ int hist[512];
    __shared__ int offs[512];
    __shared__ int cur[512];
    int g = blockIdx.x, t = threadIdx.x;
    hist[t] = 0;
    cur[t] = 0;
    __syncthreads();
    int b0 = g_bbase[g], b1 = g_bbase[g + 1];
    for (int e = b0 + t; e < b1; e += 512) {
        unsigned int p = g_ebuck[e];
        atomicAdd(&hist[p >> 16], 1);
    }
    __syncthreads();
    int v = hist[t];
    offs[t] = v;
    __syncthreads();
    for (int off = 1; off < 512; off <<= 1) {
        int u = (t >= off) ? offs[t - off] : 0;
        __syncthreads();
        offs[t] += u;
        __syncthreads();
    }
    int excl = offs[t] - v;
    g_rows1[g * 512 + t] = b0 + excl;
    if (t == 511) g_rows1[g * 512 + 512] = b0 + excl + v;
    __syncthreads();
    offs[t] = excl;
    __syncthreads();
    for (int e = b0 + t; e < b1; e += 512) {
        unsigned int p = g_ebuck[e];
        int dl = p >> 16;
        int r = atomicAdd(&cur[dl], 1);
        g_csr1u[b0 + offs[dl] + r] = (unsigned short)(p & 0xFFFFu);
    }
}

// ---------------- fused conv: agg(gather->LDS) + MFMA + epilogues -----------
// Phase 1: per-block 128-row mean aggregation (R4-proven gather shape:
//   TPN=KA/8 threads/row, 16B/thread/edge, unroll-4, fp32 accum -> bf16 LDS).
// Phase 2: out = relu([agg | root] @ W + bias); A-half from LDS, root from
//   global (BGATE: scaled by gate), MASKED rows zeroed; epilogues: pool
//   partials -> g_xc4, DOTS: score dots -> g_trel/g_troot.
// KC: 0 denom=deg; 1 denom=kept count (gather keptu) + store g_kinv; 2 read g_kinv
template <int KA, int KB, int KC, int GATED, int MASKED, int DOTS, int BGATE>
__global__ __launch_bounds__(256) void k_conv(int hId, int bId, int wId, int wOfs,
                                              const float* __restrict__ bias, int outId,
                                              int sec,
                                              const float* __restrict__ pwr,
                                              const float* __restrict__ pwt) {
    constexpr int STR = KA + 8;            // padded LDS row stride (shorts)
    __shared__ unsigned short lds_a[128 * STR];
    __shared__ float s[128];
    const unsigned short* h = ubuf(hId);
    const unsigned short* Bp = ubuf(bId);
    const unsigned short* Wt = ubuf(wId) + wOfs;
    unsigned short* out = ubuf(outId);
    int rowbase = blockIdx.x * 128;

    // ---------- phase 1: gather-aggregate into LDS ----------
    {
        constexpr int TPN = KA / 8;
        constexpr int RPP = 256 / TPN;
        int local = threadIdx.x / TPN;
        int t = threadIdx.x % TPN;
        const unsigned short* ht = h + t * 8;
#pragma unroll 1
        for (int pass = 0; pass < 128 / RPP; pass++) {
            int rl = pass * RPP + local;
            int node = rowbase + rl;
            int r0 = g_rows1[node], r1 = g_rows1[node + 1];
            float kinv_pre = (KC == 2) ? g_kinv[node] : 0.f;
            float acc[8];
#pragma unroll
            for (int i = 0; i < 8; i++) acc[i] = 0.f;
            int kc = 0;
#define ACCV(v, gf)                                              \
    acc[0] += gf * b2f((unsigned short)(v.x & 0xffff));          \
    acc[1] += gf * b2f((unsigned short)(v.x >> 16));             \
    acc[2] += gf * b2f((unsigned short)(v.y & 0xffff));          \
    acc[3] += gf * b2f((unsigned short)(v.y >> 16));             \
    acc[4] += gf * b2f((unsigned short)(v.z & 0xffff));          \
    acc[5] += gf * b2f((unsigned short)(v.z >> 16));             \
    acc[6] += gf * b2f((unsigned short)(v.w & 0xffff));          \
    acc[7] += gf * b2f((unsigned short)(v.w >> 16));
            int e = r0;
            for (; e + 4 <= r1; e += 4) {
                int i0 = g_csr1u[e], i1 = g_csr1u[e + 1];
                int i2 = g_csr1u[e + 2], i3 = g_csr1u[e + 3];
                uint4 v0 = *(const uint4*)&ht[(size_t)i0 * KA];
                uint4 v1 = *(const uint4*)&ht[(size_t)i1 * KA];
                uint4 v2 = *(const uint4*)&ht[(size_t)i2 * KA];
                uint4 v3 = *(const uint4*)&ht[(size_t)i3 * KA];
                float g0 = GATED ? g_gatef[i0] : 1.0f;
                float g1 = GATED ? g_gatef[i1] : 1.0f;
                float g2 = GATED ? g_gatef[i2] : 1.0f;
                float g3 = GATED ? g_gatef[i3] : 1.0f;
                if (KC == 1)
                    kc += (int)g_keptu[i0] + (int)g_keptu[i1]
                        + (int)g_keptu[i2] + (int)g_keptu[i3];
                ACCV(v0, g0) ACCV(v1, g1) ACCV(v2, g2) ACCV(v3, g3)
            }
            for (; e < r1; e++) {
                int i0 = g_csr1u[e];
                uint4 v0 = *(const uint4*)&ht[(size_t)i0 * KA];
                float g0 = GATED ? g_gatef[i0] : 1.0f;
                if (KC == 1) kc += (int)g_keptu[i0];
                ACCV(v0, g0)
            }
#undef ACCV
            float inv;
            if (KC == 0) {
                int c = r1 - r0;
                inv = 1.0f / (float)(c > 0 ? c : 1);
            } else if (KC == 1) {
                inv = 1.0f / (float)(kc > 0 ? kc : 1);
                if (t == 0) g_kinv[node] = inv;
            } else {
                inv = kinv_pre;
            }
            uint4 o;
            o.x = (unsigned int)f2b(acc[0] * inv) | ((unsigned int)f2b(acc[1] * inv) << 16);
            o.y = (unsigned int)f2b(acc[2] * inv) | ((unsigned int)f2b(acc[3] * inv) << 16);
            o.z = (unsigned int)f2b(acc[4] * inv) | ((unsigned int)f2b(acc[5] * inv) << 16);
            o.w = (unsigned int)f2b(acc[6] * inv) | ((unsigned int)f2b(acc[7] * inv) << 16);
            *(uint4*)&lds_a[rl * STR + t * 8] = o;
        }
    }
    __syncthreads();

    // ---------- phase 2: MFMA ----------
    const int K = KA + KB;
    int lane = threadIdx.x & 63;
    int w = threadIdx.x >> 6;
    int n16 = lane & 15, quad = lane >> 4;
    int rowloc = w * 32;
    int rowg = rowbase + rowloc;
    int g = blockIdx.x >> 2, qb = blockIdx.x & 3;
    float ga0 = BGATE ? g_gatef[rowg + n16] : 1.0f;
    float ga1 = BGATE ? g_gatef[rowg + 16 + n16] : 1.0f;
    f32x4 acc[2][8];
#pragma unroll
    for (int rt = 0; rt < 2; rt++)
#pragma unroll
        for (int ct = 0; ct < 8; ct++)
#pragma unroll
            for (int i = 0; i < 4; i++) acc[rt][ct][i] = 0.f;

#pragma unroll
    for (int ks = 0; ks < K / 32; ks++) {
        int k0 = ks * 32;
        bf16x8 a0, a1;
        if (k0 < KA) {
            a0 = *(const bf16x8*)&lds_a[(rowloc + n16) * STR + k0 + quad * 8];
            a1 = *(const bf16x8*)&lds_a[(rowloc + 16 + n16) * STR + k0 + quad * 8];
        } else {
            int kk = k0 - KA;
            a0 = *(const bf16x8*)&Bp[(size_t)(rowg + n16) * KB + kk + quad * 8];
            a1 = *(const bf16x8*)&Bp[(size_t)(rowg + 16 + n16) * KB + kk + quad * 8];
            if (BGATE) { a0 = scale8(a0, ga0); a1 = scale8(a1, ga1); }
        }
#pragma unroll
        for (int ct = 0; ct < 8; ct++) {
            bf16x8 b = *(const bf16x8*)&Wt[(size_t)(ct * 16 + n16) * K + k0 + quad * 8];
            acc[0][ct] = __builtin_amdgcn_mfma_f32_16x16x32_bf16(a0, b, acc[0][ct], 0, 0, 0);
            acc[1][ct] = __builtin_amdgcn_mfma_f32_16x16x32_bf16(a1, b, acc[1][ct], 0, 0, 0);
        }
    }

    // bias + relu + mask, store, keep values in acc
    if (threadIdx.x < 128) s[threadIdx.x] = 0.f;
#pragma unroll
    for (int rt = 0; rt < 2; rt++) {
        float m[4];
#pragma unroll
        for (int i = 0; i < 4; i++) {
            int r = rowg + rt * 16 + quad * 4 + i;
            m[i] = (!MASKED || g_keptu[r]) ? 1.0f : 0.0f;
        }
#pragma unroll
        for (int ct = 0; ct < 8; ct++) {
            int c = ct * 16 + n16;
            float bv = bias[c];
#pragma unroll
            for (int i = 0; i < 4; i++) {
                int r = rowg + rt * 16 + quad * 4 + i;
                float v = fmaxf(acc[rt][ct][i] + bv, 0.f) * m[i];
                acc[rt][ct][i] = v;
                out[(size_t)r * 128 + c] = f2b(v);
            }
        }
    }
    __syncthreads();

    // pool epilogue: column sums over this block's 128 rows
#pragma unroll
    for (int ct = 0; ct < 8; ct++) {
        float p = 0.f;
#pragma unroll
        for (int rt = 0; rt < 2; rt++)
#pragma unroll
            for (int i = 0; i < 4; i++) p += acc[rt][ct][i];
        p += __shfl_xor(p, 16);
        p += __shfl_xor(p, 32);
        if (quad == 0) atomicAdd(&s[ct * 16 + n16], p);
    }

    // DOTS epilogue (conv2): row dots with pwr/pwt
    if (DOTS) {
        float pr[8], pt[8];
#pragma unroll
        for (int ct = 0; ct < 8; ct++) {
            pr[ct] = pwr[ct * 16 + n16];
            pt[ct] = pwt[ct * 16 + n16];
        }
#pragma unroll
        for (int rt = 0; rt < 2; rt++)
#pragma unroll
            for (int i = 0; i < 4; i++) {
                float dr = 0.f, dt = 0.f;
#pragma unroll
                for (int ct = 0; ct < 8; ct++) {
                    dr += acc[rt][ct][i] * pr[ct];
                    dt += acc[rt][ct][i] * pt[ct];
                }
                dr += __shfl_xor(dr, 1); dt += __shfl_xor(dt, 1);
                dr += __shfl_xor(dr, 2); dt += __shfl_xor(dt, 2);
                dr += __shfl_xor(dr, 4); dt += __shfl_xor(dt, 4);
                dr += __shfl_xor(dr, 8); dt += __shfl_xor(dt, 8);
                if (n16 == 0) {
                    int r = rowg + rt * 16 + quad * 4 + i;
                    g_trel[r] = dr;
                    g_troot[r] = dt;
                }
            }
    }
    __syncthreads();
    if (threadIdx.x < 128)
        g_xc4[((sec * NB + g) * 4 + qb) * 128 + threadIdx.x] = s[threadIdx.x];
}

// ---------------- SAGPool: fused score + per-graph bitonic top-410 ----------
__global__ __launch_bounds__(256) void k_topk(const float* __restrict__ pb) {
    __shared__ float sv[512];
    __shared__ int si[512];
    int g = blockIdx.x, t = threadIdx.x;
    float pbv = pb[0];
    for (int l = t; l < 512; l += 256) {
        int node = g * 512 + l;
        int r0 = g_rows1[node], r1 = g_rows1[node + 1];
        float s = 0.f;
        int e = r0;
        for (; e + 4 <= r1; e += 4) {
            float s0 = g_trel[g_csr1u[e]];
            float s1 = g_trel[g_csr1u[e + 1]];
            float s2 = g_trel[g_csr1u[e + 2]];
            float s3 = g_trel[g_csr1u[e + 3]];
            s += (s0 + s1) + (s2 + s3);
        }
        for (; e < r1; e++) s += g_trel[g_csr1u[e]];
        sv[l] = s + g_troot[node] + pbv;
        si[l] = l;
    }
    __syncthreads();
    for (int k = 2; k <= 512; k <<= 1) {
        for (int j = k >> 1; j > 0; j >>= 1) {
            for (int i = t; i < 512; i += 256) {
                int p = i ^ j;
                if (p > i) {
                    float va = sv[i], vb = sv[p];
                    int ia = si[i], ib = si[p];
                    bool aFirst = (va > vb) || (va == vb && ia < ib);
                    bool up = ((i & k) == 0);
                    if (up != aFirst) { sv[i] = vb; sv[p] = va; si[i] = ib; si[p] = ia; }
                }
            }
            __syncthreads();
        }
    }
    for (int r = t; r < 512; r += 256) {
        int old = g * 512 + si[r];
        if (r < KK) {
            g_gatef[old] = tanhf(sv[r]);
            g_keptu[old] = 1;
        } else {
            g_gatef[old] = 0.f;
            g_keptu[old] = 0;
        }
    }
}

// ---------------- MLP head + log_softmax ------------------------------------
__global__ __launch_bounds__(128) void k_head(const float* __restrict__ W1, const float* __restrict__ b1,
                                              const float* __restrict__ W2, const float* __restrict__ b2,
                                              float* __restrict__ out) {
    __shared__ float xr[512];
    __shared__ float r0[128], r1[128];
    int g = blockIdx.x, t = threadIdx.x;
    for (int i = t; i < 512; i += 128) {
        int sec = i >> 7, c = i & 127;
        const float* p = &g_xc4[((sec * NB + g) * 4) * 128 + c];
        float v = p[0] + p[128] + p[256] + p[384];
        float inv = (sec < 2) ? (1.0f / 512.0f) : (1.0f / 410.0f);
        xr[i] = v * inv;
    }
    __syncthreads();
    float acc = b1[t];
    for (int k = 0; k < 512; k++) acc += xr[k] * W1[k * 128 + t];
    acc = fmaxf(acc, 0.f);
    r0[t] = acc * W2[t * 2 + 0];
    r1[t] = acc * W2[t * 2 + 1];
    __syncthreads();
    for (int off = 64; off > 0; off >>= 1) {
        if (t < off) { r0[t] += r0[t + off]; r1[t] += r1[t + off]; }
        __syncthreads();
    }
    if (t == 0) {
        float z0 = r0[0] + b2[0], z1 = r1[0] + b2[1];
        float m = fmaxf(z0, z1);
        float l = m + logf(expf(z0 - m) + expf(z1 - m));
        out[g * 2 + 0] = z0 - l;
        out[g * 2 + 1] = z1 - l;
    }
}

// ---------------- launch -----------------------------------------------------
extern "C" void kernel_launch(void* const* d_in, const int* in_sizes, int n_in,
                              void* d_out, int out_size, void* d_ws, size_t ws_size,
                              hipStream_t stream) {
    const float* x = (const float*)d_in[0];
    const int* ei = (const int*)d_in[1];
    const int* src = ei;
    const int* dst = ei + EE;
    const float* W1r = (const float*)d_in[3];
    const float* W1o = (const float*)d_in[4];
    const float* b1 = (const float*)d_in[5];
    const float* Wcr = (const float*)d_in[6];
    const float* Wco = (const float*)d_in[7];
    const float* bc = (const float*)d_in[8];
    const float* pwr = (const float*)d_in[9];
    const float* pwt = (const float*)d_in[10];
    const float* pb = (const float*)d_in[11];
    const float* l1W = (const float*)d_in[12];
    const float* l1b = (const float*)d_in[13];
    const float* l2W = (const float*)d_in[14];
    const float* l2b = (const float*)d_in[15];
    float* out = (float*)d_out;

    // ---- prep + bhist + bucket scan (one kernel, last-block scan) ----
    k_preph<<<5568, 256, 0, stream>>>(x, W1r, W1o, Wcr, Wco, dst);

    // ---- CSR1: scatter into buckets, per-graph local CSR ----
    k_bscatter<<<1024, 256, 0, stream>>>(src, dst);
    k_bcsr<<<128, 512, 0, stream>>>();

    // ---- conv1 (fused agg+mm): hb1 = relu([agg64(xb)|xb]@wt1+b1); pool sec0 ----
    k_conv<64, 64, 0, 0, 0, 0, 0><<<512, 256, 0, stream>>>(0, 0, 3, 0, b1, 1, 0, pwr, pwt);

    // ---- conv2 -> hb2; pool sec1; score dots fused ----
    k_conv<128, 128, 0, 0, 0, 1, 0><<<512, 256, 0, stream>>>(1, 1, 4, 0, bc, 2, 1, pwr, pwt);

    // ---- SAGPool: fused score + top-410 -> gatef/keptu ----
    k_topk<<<NB, 256, 0, stream>>>(pb);

    // ---- conv3: gated agg(hb2), kept-denominator, BGATE root, masked -> hb1; sec2 ----
    k_conv<128, 128, 1, 1, 1, 0, 1><<<512, 256, 0, stream>>>(2, 2, 4, 32768, bc + 128, 1, 2, pwr, pwt);

    // ---- conv4: agg(hb1), kinv reuse, masked -> hb2; sec3 ----
    k_conv<128, 128, 2, 0, 1, 0, 0><<<512, 256, 0, stream>>>(1, 1, 4, 65536, bc + 256, 2, 3, pwr, pwt);

    // ---- head ----
    k_head<<<NB, 128, 0, stream>>>(l1W, l1b, l2W, l2b, out);
}

// Round 8
// 497.565 us; speedup vs baseline: 1.7702x; 1.7702x over previous
//
#include <hip/hip_runtime.h>
#include <math.h>

#define NT 65536
#define EE 1048576
#define NB 128
#define KK 410          // kept nodes per graph = ceil(0.8*512)
#define HH 128

typedef short bf16x8 __attribute__((ext_vector_type(8)));
typedef float f32x4 __attribute__((ext_vector_type(4)));

// ---------------- device scratch -------------------------------------------
__device__ unsigned short g_xb[(size_t)NT * 64];
__device__ unsigned short g_hb1[(size_t)NT * HH];
__device__ unsigned short g_hb2[(size_t)NT * HH];
__device__ unsigned short g_wt1[128 * 128];
__device__ unsigned short g_wtc[3 * 128 * 256];
__device__ unsigned short g_csr1u[EE];   // src id per edge, grouped by dst
__device__ unsigned short g_keptu[NT];   // 1 if node kept by SAGPool
__device__ unsigned int g_ebuck[EE];     // packed (dstLocal<<16)|src, bucketed by graph
__device__ int g_bcnt[128];
__device__ int g_bbase[129];
__device__ int g_bcur[128];
__device__ float g_trel[NT];
__device__ float g_troot[NT];
__device__ float g_gatef[NT];            // tanh(score) if kept else 0
__device__ float g_kinv[NT];             // 1/max(kept-neighbor count,1)
__device__ float g_xc4[4 * NB * 4 * 128]; // pooled partials [sec][graph][quarter][128]
__device__ int g_rows1[NT + 1];

__device__ __forceinline__ unsigned short* ubuf(int id) {
    switch (id) {
        case 0: return g_xb;
        case 1: return g_hb1;
        case 2: return g_hb2;
        case 3: return g_wt1;
        case 4: return g_wtc;
    }
    return g_xb;
}

__device__ __forceinline__ float b2f(unsigned short u) {
    union { unsigned int i; float f; } v;
    v.i = ((unsigned int)u) << 16;
    return v.f;
}
__device__ __forceinline__ unsigned short f2b(float f) {
    unsigned int x = __float_as_uint(f);
    unsigned int r = x + 0x7fffu + ((x >> 16) & 1u);   // round-to-nearest-even
    return (unsigned short)(r >> 16);
}
__device__ __forceinline__ bf16x8 scale8(bf16x8 a, float g) {
    bf16x8 r;
#pragma unroll
    for (int i = 0; i < 8; i++) {
        unsigned short u = (unsigned short)a[i];
        r[i] = (short)f2b(b2f(u) * g);
    }
    return r;
}

// ---------------- prep: x->bf16, weights->bf16 [n][K], zero bcnt ------------
// NOTE (R7 post-mortem): do NOT fuse grid-wide producer->consumer handoff into
// one kernel via __threadfence on CDNA4 — per-XCD L2 non-coherence makes each
// block's device-scope fence an L2 writeback/invalidate (5568 of them = 450us).
// Kernel boundaries pay that fence exactly once.
__global__ void k_prep(const float* __restrict__ x,
                       const float* __restrict__ W1r, const float* __restrict__ W1o,
                       const float* __restrict__ Wcr, const float* __restrict__ Wco) {
    int tid = blockIdx.x * 256 + threadIdx.x;
    if (tid < 1048576) {
        float4 v = *(const float4*)&x[(size_t)tid * 4];
        unsigned int lo = (unsigned int)f2b(v.x) | ((unsigned int)f2b(v.y) << 16);
        unsigned int hi = (unsigned int)f2b(v.z) | ((unsigned int)f2b(v.w) << 16);
        *(uint2*)&g_xb[(size_t)tid * 4] = make_uint2(lo, hi);
    } else if (tid < 1048576 + 16384) {
        int r = tid - 1048576;
        int k = r & 127, n = r >> 7;
        float v = (k < 64) ? W1r[k * 128 + n] : W1o[(k - 64) * 128 + n];
        g_wt1[n * 128 + k] = f2b(v);
    } else if (tid < 1048576 + 16384 + 98304) {
        int r = tid - (1048576 + 16384);
        int l = r >> 15;
        int k = r & 255, n = (r >> 8) & 127;
        float v = (k < 128) ? Wcr[l * 16384 + k * 128 + n]
                            : Wco[l * 16384 + (k - 128) * 128 + n];
        g_wtc[l * 32768 + n * 256 + k] = f2b(v);
    } else if (tid < 1048576 + 16384 + 98304 + 128) {
        g_bcnt[tid - (1048576 + 16384 + 98304)] = 0;
    }
}

// ---------------- CSR1 build: 2-level counting sort -------------------------
__global__ __launch_bounds__(256) void k_bhist(const int* __restrict__ dst) {
    __shared__ int h[128];
    if (threadIdx.x < 128) h[threadIdx.x] = 0;
    __syncthreads();
    int e0 = (blockIdx.x * 256 + threadIdx.x) * 4;
    int4 d = *(const int4*)&dst[e0];
    atomicAdd(&h[d.x >> 9], 1);
    atomicAdd(&h[d.y >> 9], 1);
    atomicAdd(&h[d.z >> 9], 1);
    atomicAdd(&h[d.w >> 9], 1);
    __syncthreads();
    if (threadIdx.x < 128 && h[threadIdx.x]) atomicAdd(&g_bcnt[threadIdx.x], h[threadIdx.x]);
}

__global__ __launch_bounds__(128) void k_bscan() {
    __shared__ int s[128];
    int t = threadIdx.x;
    int v = g_bcnt[t];
    s[t] = v;
    __syncthreads();
    for (int off = 1; off < 128; off <<= 1) {
        int u = (t >= off) ? s[t - off] : 0;
        __syncthreads();
        s[t] += u;
        __syncthreads();
    }
    g_bbase[t] = s[t] - v;
    g_bcur[t] = s[t] - v;
    if (t == 127) g_bbase[128] = s[127];
}

__global__ __launch_bounds__(256) void k_bscatter(const int* __restrict__ src,
                                                  const int* __restrict__ dst) {
    __shared__ int h[128];
    __shared__ int base[128];
    if (threadIdx.x < 128) h[threadIdx.x] = 0;
    __syncthreads();
    int e0 = (blockIdx.x * 256 + threadIdx.x) * 4;
    int4 s = *(const int4*)&src[e0];
    int4 d = *(const int4*)&dst[e0];
    int b0 = d.x >> 9, b1 = d.y >> 9, b2 = d.z >> 9, b3 = d.w >> 9;
    atomicAdd(&h[b0], 1);
    atomicAdd(&h[b1], 1);
    atomicAdd(&h[b2], 1);
    atomicAdd(&h[b3], 1);
    __syncthreads();
    if (threadIdx.x < 128) {
        int c = h[threadIdx.x];
        base[threadIdx.x] = c ? atomicAdd(&g_bcur[threadIdx.x], c) : 0;
        h[threadIdx.x] = 0;
    }
    __syncthreads();
    int r0 = atomicAdd(&h[b0], 1);
    g_ebuck[base[b0] + r0] = ((unsigned int)(d.x & 511) << 16) | (unsigned int)s.x;
    int r1 = atomicAdd(&h[b1], 1);
    g_ebuck[base[b1] + r1] = ((unsigned int)(d.y & 511) << 16) | (unsigned int)s.y;
    int r2 = atomicAdd(&h[b2], 1);
    g_ebuck[base[b2] + r2] = ((unsigned int)(d.z & 511) << 16) | (unsigned int)s.z;
    int r3 = atomicAdd(&h[b3], 1);
    g_ebuck[base[b3] + r3] = ((unsigned int)(d.w & 511) << 16) | (unsigned int)s.w;
}

__global__ __launch_bounds__(512) void k_bcsr() {
    __shared__ int hist[512];
    __shared__ int offs[512];
    __shared__ int cur[512];
    int g = blockIdx.x, t = threadIdx.x;
    hist[t] = 0;
    cur[t] = 0;
    __syncthreads();
    int b0 = g_bbase[g], b1 = g_bbase[g + 1];
    for (int e = b0 + t; e < b1; e += 512) {
        unsigned int p = g_ebuck[e];
        atomicAdd(&hist[p >> 16], 1);
    }
    __syncthreads();
    int v = hist[t];
    offs[t] = v;
    __syncthreads();
    for (int off = 1; off < 512; off <<= 1) {
        int u = (t >= off) ? offs[t - off] : 0;
        __syncthreads();
        offs[t] += u;
        __syncthreads();
    }
    int excl = offs[t] - v;
    g_rows1[g * 512 + t] = b0 + excl;
    if (t == 511) g_rows1[g * 512 + 512] = b0 + excl + v;
    __syncthreads();
    offs[t] = excl;
    __syncthreads();
    for (int e = b0 + t; e < b1; e += 512) {
        unsigned int p = g_ebuck[e];
        int dl = p >> 16;
        int r = atomicAdd(&cur[dl], 1);
        g_csr1u[b0 + offs[dl] + r] = (unsigned short)(p & 0xFFFFu);
    }
}

// ---------------- fused conv: agg(gather->LDS) + MFMA + epilogues -----------
// Phase 1: per-block 128-row mean aggregation (R4-proven gather shape:
//   TPN=KA/8 threads/row, 16B/thread/edge, unroll-4, fp32 accum -> bf16 LDS).
// Phase 2: out = relu([agg | root] @ W + bias); A-half from LDS, root from
//   global (BGATE: scaled by gate), MASKED rows zeroed; epilogues: pool
//   partials -> g_xc4, DOTS: score dots -> g_trel/g_troot.
// KC: 0 denom=deg; 1 denom=kept count (gather keptu) + store g_kinv; 2 read g_kinv
template <int KA, int KB, int KC, int GATED, int MASKED, int DOTS, int BGATE>
__global__ __launch_bounds__(256) void k_conv(int hId, int bId, int wId, int wOfs,
                                              const float* __restrict__ bias, int outId,
                                              int sec,
                                              const float* __restrict__ pwr,
                                              const float* __restrict__ pwt) {
    constexpr int STR = KA + 8;            // padded LDS row stride (shorts)
    __shared__ unsigned short lds_a[128 * STR];
    __shared__ float s[128];
    const unsigned short* h = ubuf(hId);
    const unsigned short* Bp = ubuf(bId);
    const unsigned short* Wt = ubuf(wId) + wOfs;
    unsigned short* out = ubuf(outId);
    int rowbase = blockIdx.x * 128;

    // ---------- phase 1: gather-aggregate into LDS ----------
    {
        constexpr int TPN = KA / 8;
        constexpr int RPP = 256 / TPN;
        int local = threadIdx.x / TPN;
        int t = threadIdx.x % TPN;
        const unsigned short* ht = h + t * 8;
#pragma unroll 1
        for (int pass = 0; pass < 128 / RPP; pass++) {
            int rl = pass * RPP + local;
            int node = rowbase + rl;
            int r0 = g_rows1[node], r1 = g_rows1[node + 1];
            float kinv_pre = (KC == 2) ? g_kinv[node] : 0.f;
            float acc[8];
#pragma unroll
            for (int i = 0; i < 8; i++) acc[i] = 0.f;
            int kc = 0;
#define ACCV(v, gf)                                              \
    acc[0] += gf * b2f((unsigned short)(v.x & 0xffff));          \
    acc[1] += gf * b2f((unsigned short)(v.x >> 16));             \
    acc[2] += gf * b2f((unsigned short)(v.y & 0xffff));          \
    acc[3] += gf * b2f((unsigned short)(v.y >> 16));             \
    acc[4] += gf * b2f((unsigned short)(v.z & 0xffff));          \
    acc[5] += gf * b2f((unsigned short)(v.z >> 16));             \
    acc[6] += gf * b2f((unsigned short)(v.w & 0xffff));          \
    acc[7] += gf * b2f((unsigned short)(v.w >> 16));
            int e = r0;
            for (; e + 4 <= r1; e += 4) {
                int i0 = g_csr1u[e], i1 = g_csr1u[e + 1];
                int i2 = g_csr1u[e + 2], i3 = g_csr1u[e + 3];
                uint4 v0 = *(const uint4*)&ht[(size_t)i0 * KA];
                uint4 v1 = *(const uint4*)&ht[(size_t)i1 * KA];
                uint4 v2 = *(const uint4*)&ht[(size_t)i2 * KA];
                uint4 v3 = *(const uint4*)&ht[(size_t)i3 * KA];
                float g0 = GATED ? g_gatef[i0] : 1.0f;
                float g1 = GATED ? g_gatef[i1] : 1.0f;
                float g2 = GATED ? g_gatef[i2] : 1.0f;
                float g3 = GATED ? g_gatef[i3] : 1.0f;
                if (KC == 1)
                    kc += (int)g_keptu[i0] + (int)g_keptu[i1]
                        + (int)g_keptu[i2] + (int)g_keptu[i3];
                ACCV(v0, g0) ACCV(v1, g1) ACCV(v2, g2) ACCV(v3, g3)
            }
            for (; e < r1; e++) {
                int i0 = g_csr1u[e];
                uint4 v0 = *(const uint4*)&ht[(size_t)i0 * KA];
                float g0 = GATED ? g_gatef[i0] : 1.0f;
                if (KC == 1) kc += (int)g_keptu[i0];
                ACCV(v0, g0)
            }
#undef ACCV
            float inv;
            if (KC == 0) {
                int c = r1 - r0;
                inv = 1.0f / (float)(c > 0 ? c : 1);
            } else if (KC == 1) {
                inv = 1.0f / (float)(kc > 0 ? kc : 1);
                if (t == 0) g_kinv[node] = inv;
            } else {
                inv = kinv_pre;
            }
            uint4 o;
            o.x = (unsigned int)f2b(acc[0] * inv) | ((unsigned int)f2b(acc[1] * inv) << 16);
            o.y = (unsigned int)f2b(acc[2] * inv) | ((unsigned int)f2b(acc[3] * inv) << 16);
            o.z = (unsigned int)f2b(acc[4] * inv) | ((unsigned int)f2b(acc[5] * inv) << 16);
            o.w = (unsigned int)f2b(acc[6] * inv) | ((unsigned int)f2b(acc[7] * inv) << 16);
            *(uint4*)&lds_a[rl * STR + t * 8] = o;
        }
    }
    __syncthreads();

    // ---------- phase 2: MFMA ----------
    const int K = KA + KB;
    int lane = threadIdx.x & 63;
    int w = threadIdx.x >> 6;
    int n16 = lane & 15, quad = lane >> 4;
    int rowloc = w * 32;
    int rowg = rowbase + rowloc;
    int g = blockIdx.x >> 2, qb = blockIdx.x & 3;
    float ga0 = BGATE ? g_gatef[rowg + n16] : 1.0f;
    float ga1 = BGATE ? g_gatef[rowg + 16 + n16] : 1.0f;
    f32x4 acc[2][8];
#pragma unroll
    for (int rt = 0; rt < 2; rt++)
#pragma unroll
        for (int ct = 0; ct < 8; ct++)
#pragma unroll
            for (int i = 0; i < 4; i++) acc[rt][ct][i] = 0.f;

#pragma unroll
    for (int ks = 0; ks < K / 32; ks++) {
        int k0 = ks * 32;
        bf16x8 a0, a1;
        if (k0 < KA) {
            a0 = *(const bf16x8*)&lds_a[(rowloc + n16) * STR + k0 + quad * 8];
            a1 = *(const bf16x8*)&lds_a[(rowloc + 16 + n16) * STR + k0 + quad * 8];
        } else {
            int kk = k0 - KA;
            a0 = *(const bf16x8*)&Bp[(size_t)(rowg + n16) * KB + kk + quad * 8];
            a1 = *(const bf16x8*)&Bp[(size_t)(rowg + 16 + n16) * KB + kk + quad * 8];
            if (BGATE) { a0 = scale8(a0, ga0); a1 = scale8(a1, ga1); }
        }
#pragma unroll
        for (int ct = 0; ct < 8; ct++) {
            bf16x8 b = *(const bf16x8*)&Wt[(size_t)(ct * 16 + n16) * K + k0 + quad * 8];
            acc[0][ct] = __builtin_amdgcn_mfma_f32_16x16x32_bf16(a0, b, acc[0][ct], 0, 0, 0);
            acc[1][ct] = __builtin_amdgcn_mfma_f32_16x16x32_bf16(a1, b, acc[1][ct], 0, 0, 0);
        }
    }

    // bias + relu + mask, store, keep values in acc
    if (threadIdx.x < 128) s[threadIdx.x] = 0.f;
#pragma unroll
    for (int rt = 0; rt < 2; rt++) {
        float m[4];
#pragma unroll
        for (int i = 0; i < 4; i++) {
            int r = rowg + rt * 16 + quad * 4 + i;
            m[i] = (!MASKED || g_keptu[r]) ? 1.0f : 0.0f;
        }
#pragma unroll
        for (int ct = 0; ct < 8; ct++) {
            int c = ct * 16 + n16;
            float bv = bias[c];
#pragma unroll
            for (int i = 0; i < 4; i++) {
                int r = rowg + rt * 16 + quad * 4 + i;
                float v = fmaxf(acc[rt][ct][i] + bv, 0.f) * m[i];
                acc[rt][ct][i] = v;
                out[(size_t)r * 128 + c] = f2b(v);
            }
        }
    }
    __syncthreads();

    // pool epilogue: column sums over this block's 128 rows
#pragma unroll
    for (int ct = 0; ct < 8; ct++) {
        float p = 0.f;
#pragma unroll
        for (int rt = 0; rt < 2; rt++)
#pragma unroll
            for (int i = 0; i < 4; i++) p += acc[rt][ct][i];
        p += __shfl_xor(p, 16);
        p += __shfl_xor(p, 32);
        if (quad == 0) atomicAdd(&s[ct * 16 + n16], p);
    }

    // DOTS epilogue (conv2): row dots with pwr/pwt
    if (DOTS) {
        float pr[8], pt[8];
#pragma unroll
        for (int ct = 0; ct < 8; ct++) {
            pr[ct] = pwr[ct * 16 + n16];
            pt[ct] = pwt[ct * 16 + n16];
        }
#pragma unroll
        for (int rt = 0; rt < 2; rt++)
#pragma unroll
            for (int i = 0; i < 4; i++) {
                float dr = 0.f, dt = 0.f;
#pragma unroll
                for (int ct = 0; ct < 8; ct++) {
                    dr += acc[rt][ct][i] * pr[ct];
                    dt += acc[rt][ct][i] * pt[ct];
                }
                dr += __shfl_xor(dr, 1); dt += __shfl_xor(dt, 1);
                dr += __shfl_xor(dr, 2); dt += __shfl_xor(dt, 2);
                dr += __shfl_xor(dr, 4); dt += __shfl_xor(dt, 4);
                dr += __shfl_xor(dr, 8); dt += __shfl_xor(dt, 8);
                if (n16 == 0) {
                    int r = rowg + rt * 16 + quad * 4 + i;
                    g_trel[r] = dr;
                    g_troot[r] = dt;
                }
            }
    }
    __syncthreads();
    if (threadIdx.x < 128)
        g_xc4[((sec * NB + g) * 4 + qb) * 128 + threadIdx.x] = s[threadIdx.x];
}

// ---------------- SAGPool: fused score + per-graph bitonic top-410 ----------
__global__ __launch_bounds__(256) void k_topk(const float* __restrict__ pb) {
    __shared__ float sv[512];
    __shared__ int si[512];
    int g = blockIdx.x, t = threadIdx.x;
    float pbv = pb[0];
    for (int l = t; l < 512; l += 256) {
        int node = g * 512 + l;
        int r0 = g_rows1[node], r1 = g_rows1[node + 1];
        float s = 0.f;
        int e = r0;
        for (; e + 4 <= r1; e += 4) {
            float s0 = g_trel[g_csr1u[e]];
            float s1 = g_trel[g_csr1u[e + 1]];
            float s2 = g_trel[g_csr1u[e + 2]];
            float s3 = g_trel[g_csr1u[e + 3]];
            s += (s0 + s1) + (s2 + s3);
        }
        for (; e < r1; e++) s += g_trel[g_csr1u[e]];
        sv[l] = s + g_troot[node] + pbv;
        si[l] = l;
    }
    __syncthreads();
    for (int k = 2; k <= 512; k <<= 1) {
        for (int j = k >> 1; j > 0; j >>= 1) {
            for (int i = t; i < 512; i += 256) {
                int p = i ^ j;
                if (p > i) {
                    float va = sv[i], vb = sv[p];
                    int ia = si[i], ib = si[p];
                    bool aFirst = (va > vb) || (va == vb && ia < ib);
                    bool up = ((i & k) == 0);
                    if (up != aFirst) { sv[i] = vb; sv[p] = va; si[i] = ib; si[p] = ia; }
                }
            }
            __syncthreads();
        }
    }
    for (int r = t; r < 512; r += 256) {
        int old = g * 512 + si[r];
        if (r < KK) {
            g_gatef[old] = tanhf(sv[r]);
            g_keptu[old] = 1;
        } else {
            g_gatef[old] = 0.f;
            g_keptu[old] = 0;
        }
    }
}

// ---------------- MLP head + log_softmax ------------------------------------
__global__ __launch_bounds__(128) void k_head(const float* __restrict__ W1, const float* __restrict__ b1,
                                              const float* __restrict__ W2, const float* __restrict__ b2,
                                              float* __restrict__ out) {
    __shared__ float xr[512];
    __shared__ float r0[128], r1[128];
    int g = blockIdx.x, t = threadIdx.x;
    for (int i = t; i < 512; i += 128) {
        int sec = i >> 7, c = i & 127;
        const float* p = &g_xc4[((sec * NB + g) * 4) * 128 + c];
        float v = p[0] + p[128] + p[256] + p[384];
        float inv = (sec < 2) ? (1.0f / 512.0f) : (1.0f / 410.0f);
        xr[i] = v * inv;
    }
    __syncthreads();
    float acc = b1[t];
    for (int k = 0; k < 512; k++) acc += xr[k] * W1[k * 128 + t];
    acc = fmaxf(acc, 0.f);
    r0[t] = acc * W2[t * 2 + 0];
    r1[t] = acc * W2[t * 2 + 1];
    __syncthreads();
    for (int off = 64; off > 0; off >>= 1) {
        if (t < off) { r0[t] += r0[t + off]; r1[t] += r1[t + off]; }
        __syncthreads();
    }
    if (t == 0) {
        float z0 = r0[0] + b2[0], z1 = r1[0] + b2[1];
        float m = fmaxf(z0, z1);
        float l = m + logf(expf(z0 - m) + expf(z1 - m));
        out[g * 2 + 0] = z0 - l;
        out[g * 2 + 1] = z1 - l;
    }
}

// ---------------- launch -----------------------------------------------------
extern "C" void kernel_launch(void* const* d_in, const int* in_sizes, int n_in,
                              void* d_out, int out_size, void* d_ws, size_t ws_size,
                              hipStream_t stream) {
    const float* x = (const float*)d_in[0];
    const int* ei = (const int*)d_in[1];
    const int* src = ei;
    const int* dst = ei + EE;
    const float* W1r = (const float*)d_in[3];
    const float* W1o = (const float*)d_in[4];
    const float* b1 = (const float*)d_in[5];
    const float* Wcr = (const float*)d_in[6];
    const float* Wco = (const float*)d_in[7];
    const float* bc = (const float*)d_in[8];
    const float* pwr = (const float*)d_in[9];
    const float* pwt = (const float*)d_in[10];
    const float* pb = (const float*)d_in[11];
    const float* l1W = (const float*)d_in[12];
    const float* l1b = (const float*)d_in[13];
    const float* l2W = (const float*)d_in[14];
    const float* l2b = (const float*)d_in[15];
    float* out = (float*)d_out;

    // ---- prep (x->bf16, weights->bf16, zero bcnt) ----
    k_prep<<<(1048576 + 16384 + 98304 + 128 + 255) / 256, 256, 0, stream>>>(x, W1r, W1o, Wcr, Wco);

    // ---- CSR1 via counting sort (fence-free: kernel boundaries do the sync) ----
    k_bhist<<<1024, 256, 0, stream>>>(dst);
    k_bscan<<<1, 128, 0, stream>>>();
    k_bscatter<<<1024, 256, 0, stream>>>(src, dst);
    k_bcsr<<<128, 512, 0, stream>>>();

    // ---- conv1 (fused agg+mm): hb1 = relu([agg64(xb)|xb]@wt1+b1); pool sec0 ----
    k_conv<64, 64, 0, 0, 0, 0, 0><<<512, 256, 0, stream>>>(0, 0, 3, 0, b1, 1, 0, pwr, pwt);

    // ---- conv2 -> hb2; pool sec1; score dots fused ----
    k_conv<128, 128, 0, 0, 0, 1, 0><<<512, 256, 0, stream>>>(1, 1, 4, 0, bc, 2, 1, pwr, pwt);

    // ---- SAGPool: fused score + top-410 -> gatef/keptu ----
    k_topk<<<NB, 256, 0, stream>>>(pb);

    // ---- conv3: gated agg(hb2), kept-denominator, BGATE root, masked -> hb1; sec2 ----
    k_conv<128, 128, 1, 1, 1, 0, 1><<<512, 256, 0, stream>>>(2, 2, 4, 32768, bc + 128, 1, 2, pwr, pwt);

    // ---- conv4: agg(hb1), kinv reuse, masked -> hb2; sec3 ----
    k_conv<128, 128, 2, 0, 1, 0, 0><<<512, 256, 0, stream>>>(1, 1, 4, 65536, bc + 256, 2, 3, pwr, pwt);

    // ---- head ----
    k_head<<<NB, 128, 0, stream>>>(l1W, l1b, l2W, l2b, out);
}